// Round 3
// baseline (453.988 us; speedup 1.0000x reference)
//
#include <hip/hip_runtime.h>
#include <math.h>

namespace {
constexpr int kT = 16;
constexpr int kH = 56;
constexpr int kW = 56;
constexpr int kCAll = 256;
constexpr int kPlane = kH * kW;      // 3136
constexpr int kPlane4 = kPlane / 4;  // 784
}

// Gate layout (fp32, stored in out[frame 127]): plane index (n*2+g)*16 + t,
// each plane kPlane floats. Total = 256 planes = exactly one output frame.

// K1: gate = tanh(conv3d(relu(bn(x[:, :64])), groups=2) + b)
// One block per (n, g, t, 28-row stripe) -> 8*2*16*2 = 512 blocks.
// LDS-stage one (ic, kd) 30x58 slice (halo incl., BN+ReLU applied at load).
// Thread owns 7 contiguous pixels in one row.
__global__ __launch_bounds__(256)
void gate_conv_kernel(const float* __restrict__ x,
                      const float* __restrict__ gamma,
                      const float* __restrict__ beta,
                      const float* __restrict__ mean,
                      const float* __restrict__ var,
                      const float* __restrict__ cw,
                      const float* __restrict__ cb,
                      float* __restrict__ gate) {
  __shared__ float sm[30 * 58];
  const int bid = blockIdx.x;          // 0..511
  const int stripe = bid & 1;
  const int g = (bid >> 1) & 1;
  const int t = (bid >> 2) & 15;
  const int n = bid >> 6;              // 0..7
  const int h0 = stripe * 28;
  const int tid = threadIdx.x;

  const int r = tid >> 3;            // 0..31, active rows < 28
  const int c0 = (tid & 7) * 7;      // 8 col-groups of 7
  const bool active = (r < 28);

  float acc[7] = {0.f, 0.f, 0.f, 0.f, 0.f, 0.f, 0.f};

  for (int ic = 0; ic < 32; ++ic) {
    const int ch = g * 32 + ic;
    const float sc = gamma[ch] * rsqrtf(var[ch] + 1e-5f);
    const float sh = beta[ch] - mean[ch] * sc;
    const float* wbase = cw + ch * 27;
    for (int kd = 0; kd < 3; ++kd) {
      const int tt = t + kd - 1;
      if (tt < 0 || tt >= kT) continue;  // block-uniform: SAME-pad zeros
      const float* src = x + ((size_t)(n * kT + tt) * kCAll + ch) * kPlane;
      __syncthreads();
      for (int i = tid; i < 30 * 58; i += 256) {
        const int lr = i / 58;
        const int lc = i - lr * 58;
        const int hh = h0 + lr - 1;
        const int wc = lc - 1;
        float v = 0.f;
        if ((unsigned)hh < (unsigned)kH && (unsigned)wc < (unsigned)kW)
          v = fmaxf(0.f, fmaf(src[hh * kW + wc], sc, sh));
        sm[i] = v;
      }
      __syncthreads();
      if (active) {
        float wk[9];
        #pragma unroll
        for (int j = 0; j < 9; ++j) wk[j] = wbase[kd * 9 + j];
        #pragma unroll
        for (int kh = 0; kh < 3; ++kh) {
          const float* row = &sm[(r + kh) * 58 + c0];
          const float wa = wk[kh * 3 + 0];
          const float wb = wk[kh * 3 + 1];
          const float wcc = wk[kh * 3 + 2];
          float v[9];
          #pragma unroll
          for (int j = 0; j < 9; ++j) v[j] = row[j];
          #pragma unroll
          for (int p = 0; p < 7; ++p)
            acc[p] += v[p] * wa + v[p + 1] * wb + v[p + 2] * wcc;
        }
      }
    }
  }
  if (active) {
    const float b = cb[g];
    float* gp = gate + (((size_t)(n * 2 + g) * kT + t) * kH + (h0 + r)) * kW + c0;
    #pragma unroll
    for (int p = 0; p < 7; ++p)
      gp[p] = tanhf(acc[p] + b);
  }
}

// K1.5: copy the 3 gate planes frame-127 outputs need (g0[n7,t15]=239,
// g1[n7,t14]=254, g1[n7,t15]=255) into hole H = frame 126, channels 64..66.
__global__ __launch_bounds__(256)
void copy_gate_slice_kernel(float4* __restrict__ o4) {
  const int j = blockIdx.x * 256 + threadIdx.x;
  if (j >= 3 * kPlane4) return;
  const int q = j / kPlane4;
  const int rr = j - q * kPlane4;
  const int pidx = (q == 0) ? 239 : (q == 1 ? 254 : 255);
  const size_t G1 = (size_t)127 * kCAll * kPlane4;
  const size_t H = ((size_t)126 * kCAll + 64) * kPlane4;
  o4[H + j] = o4[G1 + (size_t)pidx * kPlane4 + rr];
}

// K2: frames 0..126. c>=64 passthrough (skip hole H); c<64 gated shift.
//   half0 (left):  out[t] = g0[t+1]*x[t+1] + x[t] - g0[t]*x[t]
//   half1 (right): out[t] = g1[t-1]*x[t-1] + x[t] - g1[t]*x[t]
//   channel regroup inverse: out k -> pre channel (k&1)*16 + (k>>1)
__global__ __launch_bounds__(256)
void shift_main_kernel(const float4* __restrict__ x4,
                       const float4* __restrict__ g4,
                       float4* __restrict__ o4) {
  const size_t total = (size_t)127 * kCAll * kPlane4;
  const size_t idx = (size_t)blockIdx.x * 256 + threadIdx.x;
  if (idx >= total) return;

  const int p = (int)(idx % kPlane4);
  const size_t rest = idx / kPlane4;
  const int c = (int)(rest % kCAll);
  const int f = (int)(rest / kCAll);

  if (c >= 64) {
    if (f == 126 && c <= 66) return;  // hole H holds gate slice until K3
    o4[idx] = x4[idx];
    return;
  }

  const int n = f >> 4;
  const int t = f & 15;
  const int half = c >> 5;
  const int k = c & 31;
  const int m = ((k & 1) << 4) + (k >> 1);
  const int src_ch = half * 32 + m;

  const size_t xcur = ((size_t)f * kCAll + src_ch) * kPlane4 + p;
  const size_t gbase = (size_t)(n * 2 + half) * kT * kPlane4 + p;

  const float4 xc = x4[xcur];
  const float4 gc = g4[gbase + (size_t)t * kPlane4];
  float4 y = make_float4(0.f, 0.f, 0.f, 0.f);
  if (half == 0) {
    if (t < kT - 1) {
      const float4 xn = x4[xcur + (size_t)kCAll * kPlane4];
      const float4 gn = g4[gbase + (size_t)(t + 1) * kPlane4];
      y.x = gn.x * xn.x; y.y = gn.y * xn.y; y.z = gn.z * xn.z; y.w = gn.w * xn.w;
    }
  } else {
    if (t > 0) {
      const float4 xp = x4[xcur - (size_t)kCAll * kPlane4];
      const float4 gp = g4[gbase + (size_t)(t - 1) * kPlane4];
      y.x = gp.x * xp.x; y.y = gp.y * xp.y; y.z = gp.z * xp.z; y.w = gp.w * xp.w;
    }
  }
  float4 res;
  res.x = y.x + (xc.x - gc.x * xc.x);
  res.y = y.y + (xc.y - gc.y * xc.y);
  res.z = y.z + (xc.z - gc.z * xc.z);
  res.w = y.w + (xc.w - gc.w * xc.w);
  o4[idx] = res;
}

// K3: frame 127 (n=7, t=15). Reads gate slices from hole H; overwrites the
// old gate region (frame 127) with final outputs.
__global__ __launch_bounds__(256)
void last_frame_kernel(const float4* __restrict__ x4,
                       float4* o4) {
  const int idx = blockIdx.x * 256 + threadIdx.x;
  if (idx >= kCAll * kPlane4) return;
  const size_t F127 = (size_t)127 * kCAll * kPlane4;
  const int p = idx % kPlane4;
  const int c = idx / kPlane4;
  if (c >= 64) { o4[F127 + idx] = x4[F127 + idx]; return; }

  const size_t H = ((size_t)126 * kCAll + 64) * kPlane4;
  const int half = c >> 5;
  const int k = c & 31;
  const int m = ((k & 1) << 4) + (k >> 1);
  const int src_ch = half * 32 + m;

  const float4 xc = x4[F127 + (size_t)src_ch * kPlane4 + p];
  float4 gc;
  float4 y = make_float4(0.f, 0.f, 0.f, 0.f);
  if (half == 0) {
    gc = o4[H + 0 * kPlane4 + p];                 // g0[t=15]; t+1 padded -> y=0
  } else {
    gc = o4[H + 2 * kPlane4 + p];                 // g1[t=15]
    const float4 gp = o4[H + 1 * kPlane4 + p];    // g1[t=14]
    const float4 xp = x4[((size_t)126 * kCAll + src_ch) * kPlane4 + p];
    y.x = gp.x * xp.x; y.y = gp.y * xp.y; y.z = gp.z * xp.z; y.w = gp.w * xp.w;
  }
  float4 res;
  res.x = y.x + (xc.x - gc.x * xc.x);
  res.y = y.y + (xc.y - gc.y * xc.y);
  res.z = y.z + (xc.z - gc.z * xc.z);
  res.w = y.w + (xc.w - gc.w * xc.w);
  o4[F127 + idx] = res;
}

// K4: hole H gets its real passthrough values.
__global__ __launch_bounds__(256)
void fix_hole_kernel(const float4* __restrict__ x4, float4* __restrict__ o4) {
  const int j = blockIdx.x * 256 + threadIdx.x;
  if (j >= 3 * kPlane4) return;
  const size_t H = ((size_t)126 * kCAll + 64) * kPlane4;
  o4[H + j] = x4[H + j];
}

extern "C" void kernel_launch(void* const* d_in, const int* in_sizes, int n_in,
                              void* d_out, int out_size, void* d_ws, size_t ws_size,
                              hipStream_t stream) {
  const float* x     = (const float*)d_in[0];
  const float* gamma = (const float*)d_in[1];
  const float* beta  = (const float*)d_in[2];
  const float* mean  = (const float*)d_in[3];
  const float* var   = (const float*)d_in[4];
  const float* cw    = (const float*)d_in[5];
  const float* cb    = (const float*)d_in[6];
  float* out = (float*)d_out;

  // Gate tensor lives in the frame-127 region of the output (exactly 1 frame).
  float* gate = out + (size_t)127 * kCAll * kPlane;

  // 8 clips * 16 t * 2 groups * 2 stripes = 512 blocks  (1024 was the OOB bug)
  gate_conv_kernel<<<512, 256, 0, stream>>>(x, gamma, beta, mean, var, cw, cb, gate);
  copy_gate_slice_kernel<<<10, 256, 0, stream>>>((float4*)out);

  const size_t total4 = (size_t)127 * kCAll * kPlane4;  // 25,489,408
  shift_main_kernel<<<(unsigned)((total4 + 255) / 256), 256, 0, stream>>>(
      (const float4*)x, (const float4*)gate, (float4*)out);

  last_frame_kernel<<<(kCAll * kPlane4 + 255) / 256, 256, 0, stream>>>(
      (const float4*)x, (float4*)out);
  fix_hole_kernel<<<10, 256, 0, stream>>>((const float4*)x, (float4*)out);
}

// Round 4
// 255.856 us; speedup vs baseline: 1.7744x; 1.7744x over previous
//
#include <hip/hip_runtime.h>
#include <math.h>

namespace {
constexpr int kT = 16;
constexpr int kH = 56;
constexpr int kW = 56;
constexpr int kCAll = 256;
constexpr int kPlane = kH * kW;      // 3136
constexpr int kPlane4 = kPlane / 4;  // 784
constexpr int kSlice = 30 * 58;      // 1740 staged words per (ic,kd) slice
}

// Gate layout (fp32, stored in out[frame 127]): plane index (n*2+g)*16 + t,
// each plane kPlane floats. Total = 256 planes = exactly one output frame.

// K1: partial conv, ic split 4-way across blocks. Grid 2048 =
// (n:8, t:16, g:2, stripe:2, icq:4). Each block: 8 ic x 3 kd = 24 stages,
// register-prefetch pipelined; partial sums atomicAdd'ed into pre-zeroed gate.
__global__ __launch_bounds__(256)
void gate_conv_kernel(const float* __restrict__ x,
                      const float* __restrict__ gamma,
                      const float* __restrict__ beta,
                      const float* __restrict__ mean,
                      const float* __restrict__ var,
                      const float* __restrict__ cw,
                      float* __restrict__ gate) {
  __shared__ float sm[kSlice];
  const int bid = blockIdx.x;          // 0..2047
  const int icq = bid & 3;
  const int stripe = (bid >> 2) & 1;
  const int g = (bid >> 3) & 1;
  const int t = (bid >> 4) & 15;
  const int n = bid >> 8;              // 0..7
  const int h0 = stripe * 28;
  const int tid = threadIdx.x;

  // Per-thread staging map (same for every slice): 7 strided elements.
  int soff[7];      // offset within a 56x56 plane, or -1 if halo-pad
  #pragma unroll
  for (int j = 0; j < 7; ++j) {
    const int i = tid + j * 256;
    int o = -1;
    if (i < kSlice) {
      const int lr = i / 58;
      const int lc = i - lr * 58;
      const int hh = h0 + lr - 1;
      const int wc = lc - 1;
      if ((unsigned)hh < (unsigned)kH && (unsigned)wc < (unsigned)kW)
        o = hh * kW + wc;
    }
    soff[j] = o;
  }

  const int r = tid >> 3;            // 0..31, active rows < 28
  const int c0 = (tid & 7) * 7;      // 8 col-groups of 7
  const bool active = (r < 28);

  float acc[7] = {0.f, 0.f, 0.f, 0.f, 0.f, 0.f, 0.f};

  // Slice s -> icl = s/3, kd = s%3, ch = g*32 + icq*8 + icl, tt = t+kd-1.
  float pre[7];
  float psc, psh;
  {  // prefetch slice 0 (kd=0 -> tt = t-1)
    const int ch = g * 32 + icq * 8;
    psc = gamma[ch] * rsqrtf(var[ch] + 1e-5f);
    psh = beta[ch] - mean[ch] * psc;
    const int tt = t - 1;
    const bool valid = (tt >= 0);
    const float* src = x + ((size_t)(n * kT + tt) * kCAll + ch) * kPlane;
    #pragma unroll
    for (int j = 0; j < 7; ++j)
      pre[j] = (valid && soff[j] >= 0) ? src[soff[j]] : 0.f;
  }

  for (int s = 0; s < 24; ++s) {
    const int icl = s / 3;
    const int kd = s - icl * 3;
    const int ch = g * 32 + icq * 8 + icl;
    const float sc = psc, sh = psh;

    __syncthreads();  // prior compute done reading sm
    #pragma unroll
    for (int j = 0; j < 7; ++j) {
      const int i = tid + j * 256;
      if (i < kSlice)
        sm[i] = (pre[j] != 0.f || soff[j] >= 0) ? fmaxf(0.f, fmaf(pre[j], sc, sh)) * (soff[j] >= 0 ? 1.f : 0.f) : 0.f;
    }
    __syncthreads();

    // Prefetch slice s+1 (overlaps with compute below).
    if (s < 23) {
      const int s1 = s + 1;
      const int icl1 = s1 / 3;
      const int kd1 = s1 - icl1 * 3;
      const int ch1 = g * 32 + icq * 8 + icl1;
      psc = gamma[ch1] * rsqrtf(var[ch1] + 1e-5f);
      psh = beta[ch1] - mean[ch1] * psc;
      const int tt1 = t + kd1 - 1;
      const bool valid1 = (tt1 >= 0 && tt1 < kT);
      const float* src1 = x + ((size_t)(n * kT + tt1) * kCAll + ch1) * kPlane;
      #pragma unroll
      for (int j = 0; j < 7; ++j)
        pre[j] = (valid1 && soff[j] >= 0) ? src1[soff[j]] : 0.f;
    }

    if (active) {
      const float* wbase = cw + ch * 27 + kd * 9;
      const int tt = t + kd - 1;
      if (tt >= 0 && tt < kT) {
        #pragma unroll
        for (int kh = 0; kh < 3; ++kh) {
          const float* row = &sm[(r + kh) * 58 + c0];
          const float wa = wbase[kh * 3 + 0];
          const float wb = wbase[kh * 3 + 1];
          const float wcc = wbase[kh * 3 + 2];
          float v[9];
          #pragma unroll
          for (int j = 0; j < 9; ++j) v[j] = row[j];
          #pragma unroll
          for (int p = 0; p < 7; ++p)
            acc[p] += v[p] * wa + v[p + 1] * wb + v[p + 2] * wcc;
        }
      }
    }
  }

  if (active) {
    float* gp = gate + (((size_t)(n * 2 + g) * kT + t) * kH + (h0 + r)) * kW + c0;
    #pragma unroll
    for (int p = 0; p < 7; ++p)
      atomicAdd(gp + p, acc[p]);
  }
}

// K1b: gate = tanh(gate + bias[g])
__global__ __launch_bounds__(256)
void gate_finish_kernel(float* __restrict__ gate, const float* __restrict__ cb) {
  const int idx = blockIdx.x * 256 + threadIdx.x;
  if (idx >= 256 * kPlane) return;
  const int plane = idx / kPlane;      // (n*2+g)*16 + t
  const int g = (plane >> 4) & 1;
  gate[idx] = tanhf(gate[idx] + cb[g]);
}

// K1.5: copy the 3 gate planes frame-127 outputs need (g0[n7,t15]=239,
// g1[n7,t14]=254, g1[n7,t15]=255) into hole H = frame 126, channels 64..66.
__global__ __launch_bounds__(256)
void copy_gate_slice_kernel(float4* __restrict__ o4) {
  const int j = blockIdx.x * 256 + threadIdx.x;
  if (j >= 3 * kPlane4) return;
  const int q = j / kPlane4;
  const int rr = j - q * kPlane4;
  const int pidx = (q == 0) ? 239 : (q == 1 ? 254 : 255);
  const size_t G1 = (size_t)127 * kCAll * kPlane4;
  const size_t H = ((size_t)126 * kCAll + 64) * kPlane4;
  o4[H + j] = o4[G1 + (size_t)pidx * kPlane4 + rr];
}

// K2: frames 0..126. c>=64 passthrough (skip hole H); c<64 gated shift.
//   half0 (left):  out[t] = g0[t+1]*x[t+1] + x[t] - g0[t]*x[t]
//   half1 (right): out[t] = g1[t-1]*x[t-1] + x[t] - g1[t]*x[t]
//   channel regroup inverse: out k -> pre channel (k&1)*16 + (k>>1)
__global__ __launch_bounds__(256)
void shift_main_kernel(const float4* __restrict__ x4,
                       const float4* __restrict__ g4,
                       float4* __restrict__ o4) {
  const size_t total = (size_t)127 * kCAll * kPlane4;
  const size_t idx = (size_t)blockIdx.x * 256 + threadIdx.x;
  if (idx >= total) return;

  const int p = (int)(idx % kPlane4);
  const size_t rest = idx / kPlane4;
  const int c = (int)(rest % kCAll);
  const int f = (int)(rest / kCAll);

  if (c >= 64) {
    if (f == 126 && c <= 66) return;  // hole H holds gate slice until K3
    o4[idx] = x4[idx];
    return;
  }

  const int n = f >> 4;
  const int t = f & 15;
  const int half = c >> 5;
  const int k = c & 31;
  const int m = ((k & 1) << 4) + (k >> 1);
  const int src_ch = half * 32 + m;

  const size_t xcur = ((size_t)f * kCAll + src_ch) * kPlane4 + p;
  const size_t gbase = (size_t)(n * 2 + half) * kT * kPlane4 + p;

  const float4 xc = x4[xcur];
  const float4 gc = g4[gbase + (size_t)t * kPlane4];
  float4 y = make_float4(0.f, 0.f, 0.f, 0.f);
  if (half == 0) {
    if (t < kT - 1) {
      const float4 xn = x4[xcur + (size_t)kCAll * kPlane4];
      const float4 gn = g4[gbase + (size_t)(t + 1) * kPlane4];
      y.x = gn.x * xn.x; y.y = gn.y * xn.y; y.z = gn.z * xn.z; y.w = gn.w * xn.w;
    }
  } else {
    if (t > 0) {
      const float4 xp = x4[xcur - (size_t)kCAll * kPlane4];
      const float4 gp = g4[gbase + (size_t)(t - 1) * kPlane4];
      y.x = gp.x * xp.x; y.y = gp.y * xp.y; y.z = gp.z * xp.z; y.w = gp.w * xp.w;
    }
  }
  float4 res;
  res.x = y.x + (xc.x - gc.x * xc.x);
  res.y = y.y + (xc.y - gc.y * xc.y);
  res.z = y.z + (xc.z - gc.z * xc.z);
  res.w = y.w + (xc.w - gc.w * xc.w);
  o4[idx] = res;
}

// K3: frame 127 (n=7, t=15). Reads gate slices from hole H; overwrites the
// old gate region (frame 127) with final outputs.
__global__ __launch_bounds__(256)
void last_frame_kernel(const float4* __restrict__ x4,
                       float4* o4) {
  const int idx = blockIdx.x * 256 + threadIdx.x;
  if (idx >= kCAll * kPlane4) return;
  const size_t F127 = (size_t)127 * kCAll * kPlane4;
  const int p = idx % kPlane4;
  const int c = idx / kPlane4;
  if (c >= 64) { o4[F127 + idx] = x4[F127 + idx]; return; }

  const size_t H = ((size_t)126 * kCAll + 64) * kPlane4;
  const int half = c >> 5;
  const int k = c & 31;
  const int m = ((k & 1) << 4) + (k >> 1);
  const int src_ch = half * 32 + m;

  const float4 xc = x4[F127 + (size_t)src_ch * kPlane4 + p];
  float4 gc;
  float4 y = make_float4(0.f, 0.f, 0.f, 0.f);
  if (half == 0) {
    gc = o4[H + 0 * kPlane4 + p];                 // g0[t=15]; t+1 padded -> y=0
  } else {
    gc = o4[H + 2 * kPlane4 + p];                 // g1[t=15]
    const float4 gp = o4[H + 1 * kPlane4 + p];    // g1[t=14]
    const float4 xp = x4[((size_t)126 * kCAll + src_ch) * kPlane4 + p];
    y.x = gp.x * xp.x; y.y = gp.y * xp.y; y.z = gp.z * xp.z; y.w = gp.w * xp.w;
  }
  float4 res;
  res.x = y.x + (xc.x - gc.x * xc.x);
  res.y = y.y + (xc.y - gc.y * xc.y);
  res.z = y.z + (xc.z - gc.z * xc.z);
  res.w = y.w + (xc.w - gc.w * xc.w);
  o4[F127 + idx] = res;
}

// K4: hole H gets its real passthrough values.
__global__ __launch_bounds__(256)
void fix_hole_kernel(const float4* __restrict__ x4, float4* __restrict__ o4) {
  const int j = blockIdx.x * 256 + threadIdx.x;
  if (j >= 3 * kPlane4) return;
  const size_t H = ((size_t)126 * kCAll + 64) * kPlane4;
  o4[H + j] = x4[H + j];
}

extern "C" void kernel_launch(void* const* d_in, const int* in_sizes, int n_in,
                              void* d_out, int out_size, void* d_ws, size_t ws_size,
                              hipStream_t stream) {
  const float* x     = (const float*)d_in[0];
  const float* gamma = (const float*)d_in[1];
  const float* beta  = (const float*)d_in[2];
  const float* mean  = (const float*)d_in[3];
  const float* var   = (const float*)d_in[4];
  const float* cw    = (const float*)d_in[5];
  const float* cb    = (const float*)d_in[6];
  float* out = (float*)d_out;

  // Gate tensor lives in the frame-127 region of the output (exactly 1 frame).
  float* gate = out + (size_t)127 * kCAll * kPlane;

  hipMemsetAsync(gate, 0, (size_t)256 * kPlane * sizeof(float), stream);

  // 8 n * 16 t * 2 g * 2 stripes * 4 icq = 2048 blocks
  gate_conv_kernel<<<2048, 256, 0, stream>>>(x, gamma, beta, mean, var, cw, gate);
  gate_finish_kernel<<<(256 * kPlane + 255) / 256, 256, 0, stream>>>(gate, cb);
  copy_gate_slice_kernel<<<10, 256, 0, stream>>>((float4*)out);

  const size_t total4 = (size_t)127 * kCAll * kPlane4;  // 25,489,408
  shift_main_kernel<<<(unsigned)((total4 + 255) / 256), 256, 0, stream>>>(
      (const float4*)x, (const float4*)gate, (float4*)out);

  last_frame_kernel<<<(kCAll * kPlane4 + 255) / 256, 256, 0, stream>>>(
      (const float4*)x, (float4*)out);
  fix_hole_kernel<<<10, 256, 0, stream>>>((const float4*)x, (float4*)out);
}